// Round 1
// baseline (746.395 us; speedup 1.0000x reference)
//
#include <hip/hip_runtime.h>

typedef __attribute__((ext_vector_type(8))) short bf16x8;
typedef __attribute__((ext_vector_type(4))) float f32x4;
typedef unsigned short u16;
typedef unsigned int u32;

__device__ __forceinline__ u16 f2bf(float f){
    u32 u; __builtin_memcpy(&u,&f,4);
    u = (u + 0x7FFFu + ((u>>16)&1u)) >> 16;
    return (u16)u;
}
__device__ __forceinline__ float bf2f(u16 h){
    u32 u = ((u32)h)<<16; float f; __builtin_memcpy(&f,&u,4); return f;
}
__device__ __forceinline__ float fast_tanh(float x){
    float e = __expf(2.f*x);
    return 1.f - 2.f/(e+1.f);
}
__device__ __forceinline__ float wval(const float* W, int d, int e){
    return (d<300 && e<300) ? W[d*300+e] : 0.f;
}

// ---------------- K0: weight prep (swizzle to MFMA fragment order) ----------
// fragment layout: frag[tile][ks][lane][j] = W[d=tile*16+(lane&15)][e=ks*32+(lane>>4)*8+j]
__global__ void k_prep(const float* __restrict__ Wy, const float* __restrict__ Wh,
                       const float* __restrict__ Wp, const float* __restrict__ Wx,
                       const float* __restrict__ w,
                       u16* __restrict__ wy_swz, u16* __restrict__ wh_swz,
                       u16* __restrict__ wpx_swz, float* __restrict__ w_pad)
{
    int gid = blockIdx.x*256 + threadIdx.x;
    if (gid < 320) w_pad[gid] = (gid < 300) ? w[gid] : 0.f;
    u16* dst; const float* A; const float* Bm = nullptr; int t, nks;
    if (gid < 12800)      { dst = wy_swz;  t = gid;        nks = 10; A = Wy; }
    else if (gid < 25600) { dst = wh_swz;  t = gid-12800;  nks = 10; A = Wh; }
    else                  { dst = wpx_swz; t = gid-25600;  nks = 20; A = Wp; Bm = Wx; }
    int ks   = (t/64) % nks;
    int tile = t/(nks*64);
    int lane = t & 63;
    int d  = tile*16 + (lane & 15);
    int kb = ks*32 + (lane>>4)*8;
    u32 pk[4];
    #pragma unroll
    for (int jj=0; jj<4; jj++){
        int k0 = kb + 2*jj, k1 = k0 + 1;
        float v0, v1;
        if (Bm){ v0 = (k0 < 320) ? wval(A,d,k0) : wval(Bm,d,k0-320);
                 v1 = (k1 < 320) ? wval(A,d,k1) : wval(Bm,d,k1-320); }
        else   { v0 = wval(A,d,k0); v1 = wval(A,d,k1); }
        pk[jj] = (u32)f2bf(v0) | ((u32)f2bf(v1) << 16);
    }
    uint4 u; u.x = pk[0]; u.y = pk[1]; u.z = pk[2]; u.w = pk[3];
    ((uint4*)dst)[t] = u;
}

// ---------------- K1: Whh = h_n @ Wh^T  ->  bf16 [B][320] -------------------
__global__ __launch_bounds__(256,2) void k_whh(const float* __restrict__ hn,
        const u16* __restrict__ wh_swz, u16* __restrict__ whh)
{
    __shared__ __align__(16) u16 A[64*328];
    int tid = threadIdx.x;
    int m0 = blockIdx.x*64;
    for (int i = tid; i < 9600; i += 256){
        int r = i/150, c = (i%150)*2;
        float2 v = *(const float2*)(hn + (size_t)(m0+r)*300 + c);
        *(u32*)&A[r*328 + c] = (u32)f2bf(v.x) | ((u32)f2bf(v.y) << 16);
    }
    for (int i = tid; i < 64*28; i += 256){ int r = i/28, c = 300 + (i%28); A[r*328+c] = 0; }
    __syncthreads();
    int w = tid>>6, lane = tid&63, lo = lane&15, hi = lane>>4;
    f32x4 acc[20];
    #pragma unroll
    for (int nt=0; nt<20; nt++) acc[nt] = (f32x4){0.f,0.f,0.f,0.f};
    const bf16x8* wsz = (const bf16x8*)wh_swz;
    for (int ks=0; ks<10; ks++){
        bf16x8 aF = *(const bf16x8*)&A[(w*16+lo)*328 + ks*32 + hi*8];
        #pragma unroll
        for (int nt=0; nt<20; nt++){
            bf16x8 bF = wsz[(nt*10+ks)*64 + lane];
            acc[nt] = __builtin_amdgcn_mfma_f32_16x16x32_bf16(aF, bF, acc[nt], 0,0,0);
        }
    }
    #pragma unroll
    for (int nt=0; nt<20; nt++)
      #pragma unroll
      for (int rg=0; rg<4; rg++){
        int m = m0 + w*16 + hi*4 + rg;
        whh[(size_t)m*320 + nt*16 + lo] = f2bf(acc[nt][rg]);
      }
}

// ---------------- K2: fused attention main (2 batches / block) --------------
__global__ __launch_bounds__(256,2) void k_attn(const float* __restrict__ Y,
        const u16* __restrict__ whh, const u16* __restrict__ wy_swz,
        const float* __restrict__ w_pad, u16* __restrict__ r_out)
{
    __shared__ __align__(16) u16 Ylds[112*328];     // [col=(b,l) pad 112][e pad 328] bf16
    __shared__ float whh_s[2][320];
    __shared__ float w_s[320];
    __shared__ float s_red[4][112];
    __shared__ float alpha_s[2][64];
    int tid = threadIdx.x;
    int b0 = blockIdx.x*2;
    int w = tid>>6, lane = tid&63, lo = lane&15, hi = lane>>4;

    // stage Y (transpose f32[e][l] -> bf16 lds[col][e]), line-coalesced loads
    for (int s = w; s < 80; s += 4){
        int bb = s/40, rem = s%40;
        int e0 = (rem>>2)*32, l0 = (rem&3)*16;
        int l = l0 + lo;
        int eb = e0 + hi*8;
        const float* yb = Y + (size_t)(b0+bb)*15000;
        float v[8];
        #pragma unroll
        for (int j=0; j<8; j++){
            int e = eb + j;
            v[j] = (l < 50 && e < 300) ? yb[e*50 + l] : 0.f;
        }
        if (l < 50){
            u32 pk[4];
            #pragma unroll
            for (int jj=0; jj<4; jj++)
                pk[jj] = (u32)f2bf(v[2*jj]) | ((u32)f2bf(v[2*jj+1]) << 16);
            uint4 u; u.x = pk[0]; u.y = pk[1]; u.z = pk[2]; u.w = pk[3];
            *(uint4*)&Ylds[(bb*50 + l)*328 + eb] = u;
        }
    }
    for (int i = tid; i < 12*164; i += 256){        // zero pad cols 100..111
        int c = 100 + i/164, e2 = (i%164)*2;
        *(u32*)&Ylds[c*328 + e2] = 0;
    }
    for (int i = tid; i < 640; i += 256){
        int bb = i/320, d = i%320;
        whh_s[bb][d] = bf2f(whh[(size_t)(b0+bb)*320 + d]);
    }
    for (int i = tid; i < 320; i += 256) w_s[i] = w_pad[i];
    __syncthreads();

    // G = Wy * Yb : wave owns d-tiles {w,w+4,...,w+16}, all 7 col-tiles
    f32x4 acc[5][7];
    #pragma unroll
    for (int q=0;q<5;q++)
      #pragma unroll
      for (int ct=0;ct<7;ct++) acc[q][ct] = (f32x4){0.f,0.f,0.f,0.f};
    const bf16x8* wyf = (const bf16x8*)wy_swz;
    for (int ks=0; ks<10; ks++){
        bf16x8 aF[5];
        #pragma unroll
        for (int q=0;q<5;q++){
            int dt = w + 4*q;
            aF[q] = wyf[(dt*10+ks)*64 + lane];
        }
        #pragma unroll
        for (int ct=0; ct<7; ct++){
            bf16x8 bF = *(const bf16x8*)&Ylds[(ct*16+lo)*328 + ks*32 + hi*8];
            #pragma unroll
            for (int q=0;q<5;q++)
                acc[q][ct] = __builtin_amdgcn_mfma_f32_16x16x32_bf16(aF[q], bF, acc[q][ct], 0,0,0);
        }
    }

    // tanh + w-weighted reduction over d
    float sp[7];
    #pragma unroll
    for (int ct=0;ct<7;ct++) sp[ct] = 0.f;
    #pragma unroll
    for (int q=0;q<5;q++){
        #pragma unroll
        for (int rg=0;rg<4;rg++){
            int d = (w+4*q)*16 + hi*4 + rg;
            float wh0 = whh_s[0][d], wh1 = whh_s[1][d], wd = w_s[d];
            #pragma unroll
            for (int ct=0;ct<7;ct++){
                int col = ct*16 + lo;
                float x = acc[q][ct][rg] + (col >= 50 ? wh1 : wh0);
                sp[ct] += wd * fast_tanh(x);
            }
        }
    }
    #pragma unroll
    for (int ct=0;ct<7;ct++){
        sp[ct] += __shfl_xor(sp[ct], 16);
        sp[ct] += __shfl_xor(sp[ct], 32);
    }
    if (lane < 16){
        #pragma unroll
        for (int ct=0;ct<7;ct++) s_red[w][ct*16 + lane] = sp[ct];
    }
    __syncthreads();

    // softmax over l (wave 0 -> batch 0, wave 1 -> batch 1)
    if (w < 2){
        int bb = w;
        float sv = -1e30f;
        if (lane < 50){
            int col = bb*50 + lane;
            sv = s_red[0][col] + s_red[1][col] + s_red[2][col] + s_red[3][col];
        }
        float mx = sv;
        #pragma unroll
        for (int off=32; off; off>>=1) mx = fmaxf(mx, __shfl_xor(mx, off));
        float p = (lane < 50) ? __expf(sv - mx) : 0.f;
        float sm = p;
        #pragma unroll
        for (int off=32; off; off>>=1) sm += __shfl_xor(sm, off);
        alpha_s[bb][lane] = p / sm;
    }
    __syncthreads();

    // r[b][d] = sum_l Y[b][d][l] * alpha[b][l]  (bf16 out, padded to 320)
    for (int d = tid; d < 320; d += 256){
        float r0 = 0.f, r1 = 0.f;
        if (d < 300){
            for (int l=0; l<50; l++){
                r0 += bf2f(Ylds[l*328 + d])      * alpha_s[0][l];
                r1 += bf2f(Ylds[(50+l)*328 + d]) * alpha_s[1][l];
            }
        }
        r_out[(size_t)b0*320 + d]     = f2bf(r0);
        r_out[(size_t)(b0+1)*320 + d] = f2bf(r1);
    }
}

// ---------------- K3: h = tanh([r|hn] @ [Wp|Wx]^T) --------------------------
__global__ __launch_bounds__(256,2) void k_out(const u16* __restrict__ r_in,
        const float* __restrict__ hn, const u16* __restrict__ wpx_swz,
        float* __restrict__ out)
{
    __shared__ __align__(16) u16 A[64*648];
    int tid = threadIdx.x;
    int m0 = blockIdx.x*64;
    for (int i = tid; i < 64*40; i += 256){           // r bf16 -> cols 0..319
        int r = i/40, c8 = (i%40)*8;
        uint4 v = *(const uint4*)&r_in[(size_t)(m0+r)*320 + c8];
        *(uint4*)&A[r*648 + c8] = v;
    }
    for (int i = tid; i < 9600; i += 256){            // hn f32 -> cols 320..619
        int r = i/150, c = (i%150)*2;
        float2 v = *(const float2*)(hn + (size_t)(m0+r)*300 + c);
        *(u32*)&A[r*648 + 320 + c] = (u32)f2bf(v.x) | ((u32)f2bf(v.y) << 16);
    }
    for (int i = tid; i < 64*28; i += 256){ int r = i/28, c = 620 + (i%28); A[r*648+c] = 0; }
    __syncthreads();
    int w = tid>>6, lane = tid&63, lo = lane&15, hi = lane>>4;
    f32x4 acc[20];
    #pragma unroll
    for (int nt=0; nt<20; nt++) acc[nt] = (f32x4){0.f,0.f,0.f,0.f};
    const bf16x8* wsz = (const bf16x8*)wpx_swz;
    for (int ks=0; ks<20; ks++){
        bf16x8 aF = *(const bf16x8*)&A[(w*16+lo)*648 + ks*32 + hi*8];
        #pragma unroll
        for (int nt=0; nt<20; nt++){
            bf16x8 bF = wsz[(nt*20+ks)*64 + lane];
            acc[nt] = __builtin_amdgcn_mfma_f32_16x16x32_bf16(aF, bF, acc[nt], 0,0,0);
        }
    }
    #pragma unroll
    for (int nt=0; nt<20; nt++)
      #pragma unroll
      for (int rg=0; rg<4; rg++){
        int n = nt*16 + lo;
        if (n < 300){
            int m = m0 + w*16 + hi*4 + rg;
            out[(size_t)m*300 + n] = fast_tanh(acc[nt][rg]);
        }
      }
}

extern "C" void kernel_launch(void* const* d_in, const int* in_sizes, int n_in,
                              void* d_out, int out_size, void* d_ws, size_t ws_size,
                              hipStream_t stream)
{
    const float* Y  = (const float*)d_in[0];
    const float* hn = (const float*)d_in[1];
    const float* Wy = (const float*)d_in[2];
    const float* Wh = (const float*)d_in[3];
    const float* Wp = (const float*)d_in[4];
    const float* Wx = (const float*)d_in[5];
    const float* w  = (const float*)d_in[6];
    int B = in_sizes[1] / 300;                       // 16384

    char* ws = (char*)d_ws;
    u16*   wy_swz  = (u16*)(ws + 0);                 // 204800 B
    u16*   wh_swz  = (u16*)(ws + 204800);            // 204800 B
    u16*   wpx_swz = (u16*)(ws + 409600);            // 409600 B
    float* w_pad   = (float*)(ws + 819200);          // 1280 B
    u16*   whh     = (u16*)(ws + 820480);            // B*320*2
    u16*   r_ws    = (u16*)(ws + 820480 + (size_t)B*640);

    k_prep<<<200, 256, 0, stream>>>(Wy, Wh, Wp, Wx, w, wy_swz, wh_swz, wpx_swz, w_pad);
    k_whh <<<B/64, 256, 0, stream>>>(hn, wh_swz, whh);
    k_attn<<<B/2, 256, 0, stream>>>(Y, whh, wy_swz, w_pad, (u16*)r_ws);
    k_out <<<B/64, 256, 0, stream>>>(r_ws, hn, wpx_swz, (float*)d_out);
}

// Round 2
// 707.419 us; speedup vs baseline: 1.0551x; 1.0551x over previous
//
#include <hip/hip_runtime.h>
#include <hip/hip_bf16.h>

typedef __attribute__((ext_vector_type(8))) short bf16x8;
typedef __attribute__((ext_vector_type(4))) float f32x4;
typedef unsigned short u16;
typedef unsigned int u32;

__device__ __forceinline__ u16 f2bf(float f){
    u32 u; __builtin_memcpy(&u,&f,4);
    u = (u + 0x7FFFu + ((u>>16)&1u)) >> 16;
    return (u16)u;
}
__device__ __forceinline__ float bf2f(u16 h){
    u32 u = ((u32)h)<<16; float f; __builtin_memcpy(&f,&u,4); return f;
}
__device__ __forceinline__ u32 pkbf(float a, float b){
    __hip_bfloat162 h = __float22bfloat162_rn(float2{a,b});
    u32 r; __builtin_memcpy(&r,&h,4); return r;
}
__device__ __forceinline__ float fast_tanh(float x){
    float e = __expf(2.f*x);
    return 1.f - 2.f/(e+1.f);
}
__device__ __forceinline__ float wval(const float* W, int d, int e){
    return (d<300 && e<300) ? W[d*300+e] : 0.f;
}

// ---------------- K0: weight prep (swizzle to MFMA fragment order) ----------
// frag[tile][ks][lane][j] = W[d=tile*16+(lane&15)][e=ks*32+(lane>>4)*8+j]
__global__ void k_prep(const float* __restrict__ Wy, const float* __restrict__ Wh,
                       const float* __restrict__ Wp, const float* __restrict__ Wx,
                       const float* __restrict__ w,
                       u16* __restrict__ wy_swz, u16* __restrict__ wh_swz,
                       u16* __restrict__ wpx_swz, float* __restrict__ w_pad)
{
    int gid = blockIdx.x*256 + threadIdx.x;
    if (gid < 320) w_pad[gid] = (gid < 300) ? w[gid] : 0.f;
    u16* dst; const float* A; const float* Bm = nullptr; int t, nks;
    if (gid < 12800)      { dst = wy_swz;  t = gid;        nks = 10; A = Wy; }
    else if (gid < 25600) { dst = wh_swz;  t = gid-12800;  nks = 10; A = Wh; }
    else                  { dst = wpx_swz; t = gid-25600;  nks = 20; A = Wp; Bm = Wx; }
    int ks   = (t/64) % nks;
    int tile = t/(nks*64);
    int lane = t & 63;
    int d  = tile*16 + (lane & 15);
    int kb = ks*32 + (lane>>4)*8;
    u32 pk[4];
    #pragma unroll
    for (int jj=0; jj<4; jj++){
        int k0 = kb + 2*jj, k1 = k0 + 1;
        float v0, v1;
        if (Bm){ v0 = (k0 < 320) ? wval(A,d,k0) : wval(Bm,d,k0-320);
                 v1 = (k1 < 320) ? wval(A,d,k1) : wval(Bm,d,k1-320); }
        else   { v0 = wval(A,d,k0); v1 = wval(A,d,k1); }
        pk[jj] = (u32)f2bf(v0) | ((u32)f2bf(v1) << 16);
    }
    uint4 u; u.x = pk[0]; u.y = pk[1]; u.z = pk[2]; u.w = pk[3];
    ((uint4*)dst)[t] = u;
}

// ---------------- K1: Whh = h_n @ Wh^T  ->  bf16 [B][320] -------------------
// grid = 2*(B/64): blockIdx = rb*2 + half; half picks nt range
__global__ __launch_bounds__(256,3) void k_whh(const float* __restrict__ hn,
        const u16* __restrict__ wh_swz, u16* __restrict__ whh)
{
    __shared__ __align__(16) u16 A[64*328];
    int tid = threadIdx.x;
    int rb = blockIdx.x >> 1, half = blockIdx.x & 1;
    int m0 = rb*64;
    for (int i = tid; i < 9600; i += 256){
        int r = i/150, c = (i%150)*2;
        float2 v = *(const float2*)(hn + (size_t)(m0+r)*300 + c);
        *(u32*)&A[r*328 + c] = pkbf(v.x, v.y);
    }
    for (int i = tid; i < 64*14; i += 256){ int r = i/14, c = 300 + (i%14)*2; *(u32*)&A[r*328+c] = 0; }
    __syncthreads();
    int w = tid>>6, lane = tid&63, lo = lane&15, hi = lane>>4;
    f32x4 acc[10];
    #pragma unroll
    for (int t=0; t<10; t++) acc[t] = (f32x4){0.f,0.f,0.f,0.f};
    const bf16x8* wsz = (const bf16x8*)wh_swz;
    for (int ks=0; ks<10; ks++){
        bf16x8 aF = *(const bf16x8*)&A[(w*16+lo)*328 + ks*32 + hi*8];
        #pragma unroll
        for (int t=0; t<10; t++){
            int nt = half*10 + t;
            bf16x8 bF = wsz[(nt*10+ks)*64 + lane];
            acc[t] = __builtin_amdgcn_mfma_f32_16x16x32_bf16(aF, bF, acc[t], 0,0,0);
        }
    }
    #pragma unroll
    for (int t=0; t<10; t++)
      #pragma unroll
      for (int rg=0; rg<4; rg++){
        int m = m0 + w*16 + hi*4 + rg;
        whh[(size_t)m*320 + (half*10+t)*16 + lo] = f2bf(acc[t][rg]);
      }
}

// ---------------- K2: fused attention main (1 batch / block) ----------------
__global__ __launch_bounds__(256,3) void k_attn(const float* __restrict__ Y,
        const u16* __restrict__ whh, const u16* __restrict__ wy_swz,
        const float* __restrict__ w_pad, u16* __restrict__ r_out)
{
    constexpr int RS = 344;                      // row stride (u16), 2-way banks, 16B aligned
    __shared__ __align__(16) u16 Ylds[64*RS];    // [col=l pad 64][e pad 320] bf16
    __shared__ float whh_s[320];
    __shared__ float w_s[320];
    __shared__ float s_red[4][64];
    __shared__ float alpha_s[64];
    int tid = threadIdx.x;
    int b = blockIdx.x;
    int w = tid>>6, lane = tid&63, lo = lane&15, hi = lane>>4;

    // ---- stage Y^T (f32[e][l] -> bf16 lds[l][e]), 2-deep pipelined gather ----
    {
        int l = w*16 + lo;                        // fixed per thread
        const float* p = Y + (size_t)b*15000 + (size_t)hi*400 + l;  // e base = hi*8
        if (l < 50){
            float va[8], vb[8];
#define LOADT(k, dst) do{                                                   \
            const float* pk_ = p + (k)*1600;                                \
            if ((k) == 9){                                                  \
                _Pragma("unroll")                                           \
                for (int j=0;j<8;j++){ int e_ = 288 + hi*8 + j;             \
                    dst[j] = (e_<300) ? pk_[j*50] : 0.f; }                  \
            } else {                                                        \
                _Pragma("unroll")                                           \
                for (int j=0;j<8;j++) dst[j] = pk_[j*50];                   \
            } }while(0)
#define STORET(k, src) do{                                                  \
            uint4 uu;                                                       \
            uu.x = pkbf(src[0],src[1]); uu.y = pkbf(src[2],src[3]);         \
            uu.z = pkbf(src[4],src[5]); uu.w = pkbf(src[6],src[7]);         \
            *(uint4*)&Ylds[l*RS + (k)*32 + hi*8] = uu; }while(0)
            LOADT(0, va);
            #pragma unroll
            for (int kk=0; kk<5; kk++){
                const int k0 = 2*kk, k1 = 2*kk+1;
                LOADT(k1, vb);
                STORET(k0, va);
                if (k1 < 9) LOADT(k1+1, va);
                STORET(k1, vb);
            }
#undef LOADT
#undef STORET
        }
    }
    // zero rows 50..63 over e 0..319
    for (int i = tid; i < 14*160; i += 256){
        int r = 50 + i/160, c2 = (i%160)*2;
        *(u32*)&Ylds[r*RS + c2] = 0;
    }
    for (int i = tid; i < 160; i += 256){
        u32 z = *(const u32*)&whh[(size_t)b*320 + 2*i];
        whh_s[2*i]   = bf2f((u16)(z & 0xffff));
        whh_s[2*i+1] = bf2f((u16)(z >> 16));
    }
    for (int i = tid; i < 320; i += 256) w_s[i] = w_pad[i];
    __syncthreads();

    // ---- G = Wy * Yb : wave owns d-tiles {w, w+4, ..., w+16}, cts 0..3 ----
    f32x4 acc[5][4];
    #pragma unroll
    for (int q=0;q<5;q++)
      #pragma unroll
      for (int ct=0;ct<4;ct++) acc[q][ct] = (f32x4){0.f,0.f,0.f,0.f};
    const bf16x8* wyf = (const bf16x8*)wy_swz;
    for (int ks=0; ks<10; ks++){
        bf16x8 bF[4];
        #pragma unroll
        for (int ct=0;ct<4;ct++)
            bF[ct] = *(const bf16x8*)&Ylds[(ct*16+lo)*RS + ks*32 + hi*8];
        #pragma unroll
        for (int q=0;q<5;q++){
            bf16x8 aF = wyf[((w+4*q)*10+ks)*64 + lane];
            #pragma unroll
            for (int ct=0;ct<4;ct++)
                acc[q][ct] = __builtin_amdgcn_mfma_f32_16x16x32_bf16(aF, bF[ct], acc[q][ct], 0,0,0);
        }
    }

    // ---- tanh + w-weighted reduction over d ----
    float sp[4] = {0.f,0.f,0.f,0.f};
    #pragma unroll
    for (int q=0;q<5;q++){
        #pragma unroll
        for (int rg=0;rg<4;rg++){
            int d = (w+4*q)*16 + hi*4 + rg;
            float wh = whh_s[d], wd_ = w_s[d];
            #pragma unroll
            for (int ct=0;ct<4;ct++)
                sp[ct] += wd_ * fast_tanh(acc[q][ct][rg] + wh);
        }
    }
    #pragma unroll
    for (int ct=0;ct<4;ct++){
        sp[ct] += __shfl_xor(sp[ct], 16);
        sp[ct] += __shfl_xor(sp[ct], 32);
    }
    if (lane < 16){
        #pragma unroll
        for (int ct=0;ct<4;ct++) s_red[w][ct*16 + lane] = sp[ct];
    }
    __syncthreads();

    // ---- softmax over l (wave 0) ----
    if (w == 0){
        float sv = (lane < 50)
            ? (s_red[0][lane] + s_red[1][lane] + s_red[2][lane] + s_red[3][lane])
            : -1e30f;
        float mx = sv;
        #pragma unroll
        for (int off=32; off; off>>=1) mx = fmaxf(mx, __shfl_xor(mx, off));
        float pv = (lane < 50) ? __expf(sv - mx) : 0.f;
        float sm = pv;
        #pragma unroll
        for (int off=32; off; off>>=1) sm += __shfl_xor(sm, off);
        alpha_s[lane] = pv / sm;
    }
    __syncthreads();

    // ---- r[d] = sum_l Y[d][l] * alpha[l] (u32-pair reads, bf16 out) ----
    if (tid < 160){
        float r0 = 0.f, r1 = 0.f;
        #pragma unroll 10
        for (int l=0; l<50; l++){
            u32 z = *(const u32*)&Ylds[l*RS + 2*tid];
            float a = alpha_s[l];
            r0 += a * bf2f((u16)(z & 0xffff));
            r1 += a * bf2f((u16)(z >> 16));
        }
        *(u32*)&r_out[(size_t)b*320 + 2*tid] = pkbf(r0, r1);
    }
}

// ---------------- K3: h = tanh([r|hn] @ [Wp|Wx]^T), 32 rows/block -----------
__global__ __launch_bounds__(256,3) void k_out(const u16* __restrict__ r_in,
        const float* __restrict__ hn, const u16* __restrict__ wpx_swz,
        float* __restrict__ out)
{
    __shared__ __align__(16) u16 A[32*648];
    int tid = threadIdx.x;
    int m0 = blockIdx.x*32;
    for (int i = tid; i < 32*40; i += 256){           // r bf16 -> cols 0..319
        int r = i/40, c8 = (i%40)*8;
        uint4 v = *(const uint4*)&r_in[(size_t)(m0+r)*320 + c8];
        *(uint4*)&A[r*648 + c8] = v;
    }
    for (int i = tid; i < 32*150; i += 256){          // hn f32 -> cols 320..619
        int r = i/150, c = (i%150)*2;
        float2 v = *(const float2*)(hn + (size_t)(m0+r)*300 + c);
        *(u32*)&A[r*648 + 320 + c] = pkbf(v.x, v.y);
    }
    for (int i = tid; i < 32*14; i += 256){ int r = i/14, c = 620 + (i%14)*2; *(u32*)&A[r*648+c] = 0; }
    __syncthreads();
    int w = tid>>6, lane = tid&63, lo = lane&15, hi = lane>>4;
    int wm = w & 1, wn = w >> 1;
    f32x4 acc[10];
    #pragma unroll
    for (int t=0; t<10; t++) acc[t] = (f32x4){0.f,0.f,0.f,0.f};
    const bf16x8* wsz = (const bf16x8*)wpx_swz;
    for (int ks=0; ks<20; ks++){
        bf16x8 aF = *(const bf16x8*)&A[(wm*16+lo)*648 + ks*32 + hi*8];
        #pragma unroll
        for (int t=0; t<10; t++){
            int nt = wn*10 + t;
            bF_decl: ;
            bf16x8 bF = wsz[(nt*20+ks)*64 + lane];
            acc[t] = __builtin_amdgcn_mfma_f32_16x16x32_bf16(aF, bF, acc[t], 0,0,0);
        }
    }
    #pragma unroll
    for (int t=0; t<10; t++){
        int n = (wn*10+t)*16 + lo;
        if (n < 300){
            #pragma unroll
            for (int rg=0; rg<4; rg++){
                int m = m0 + wm*16 + hi*4 + rg;
                out[(size_t)m*300 + n] = fast_tanh(acc[t][rg]);
            }
        }
    }
}

extern "C" void kernel_launch(void* const* d_in, const int* in_sizes, int n_in,
                              void* d_out, int out_size, void* d_ws, size_t ws_size,
                              hipStream_t stream)
{
    const float* Y  = (const float*)d_in[0];
    const float* hn = (const float*)d_in[1];
    const float* Wy = (const float*)d_in[2];
    const float* Wh = (const float*)d_in[3];
    const float* Wp = (const float*)d_in[4];
    const float* Wx = (const float*)d_in[5];
    const float* w  = (const float*)d_in[6];
    int B = in_sizes[1] / 300;                       // 16384

    char* ws = (char*)d_ws;
    u16*   wy_swz  = (u16*)(ws + 0);                 // 204800 B
    u16*   wh_swz  = (u16*)(ws + 204800);            // 204800 B
    u16*   wpx_swz = (u16*)(ws + 409600);            // 409600 B
    float* w_pad   = (float*)(ws + 819200);          // 1280 B
    u16*   whh     = (u16*)(ws + 820480);            // B*320*2
    u16*   r_ws    = (u16*)(ws + 820480 + (size_t)B*640);

    k_prep<<<200, 256, 0, stream>>>(Wy, Wh, Wp, Wx, w, wy_swz, wh_swz, wpx_swz, w_pad);
    k_whh <<<(B/64)*2, 256, 0, stream>>>(hn, wh_swz, whh);
    k_attn<<<B, 256, 0, stream>>>(Y, whh, wy_swz, w_pad, r_ws);
    k_out <<<B/32, 256, 0, stream>>>(r_ws, hn, wpx_swz, (float*)d_out);
}

// Round 3
// 608.981 us; speedup vs baseline: 1.2256x; 1.1616x over previous
//
#include <hip/hip_runtime.h>
#include <hip/hip_bf16.h>

typedef __attribute__((ext_vector_type(8))) short bf16x8;
typedef __attribute__((ext_vector_type(4))) float f32x4;
typedef unsigned short u16;
typedef unsigned int u32;

__device__ __forceinline__ u16 f2bf(float f){
    u32 u; __builtin_memcpy(&u,&f,4);
    u = (u + 0x7FFFu + ((u>>16)&1u)) >> 16;
    return (u16)u;
}
__device__ __forceinline__ float bf2f(u16 h){
    u32 u = ((u32)h)<<16; float f; __builtin_memcpy(&f,&u,4); return f;
}
__device__ __forceinline__ u32 pkbf(float a, float b){
    __hip_bfloat162 h = __float22bfloat162_rn(float2{a,b});
    u32 r; __builtin_memcpy(&r,&h,4); return r;
}
__device__ __forceinline__ float fast_tanh(float x){
    float e = __expf(2.f*x);
    return 1.f - 2.f/(e+1.f);
}
__device__ __forceinline__ float wval(const float* W, int d, int e){
    return (d<300 && e<300) ? W[d*300+e] : 0.f;
}

// ---------------- K0: weight prep (swizzle to MFMA fragment order) ----------
// frag[tile][ks][lane][j] = W[d=tile*16+(lane&15)][e=ks*32+(lane>>4)*8+j]
__global__ void k_prep(const float* __restrict__ Wy, const float* __restrict__ Wh,
                       const float* __restrict__ Wp, const float* __restrict__ Wx,
                       const float* __restrict__ w,
                       u16* __restrict__ wy_swz, u16* __restrict__ wh_swz,
                       u16* __restrict__ wpx_swz, float* __restrict__ w_pad)
{
    int gid = blockIdx.x*256 + threadIdx.x;
    if (gid < 320) w_pad[gid] = (gid < 300) ? w[gid] : 0.f;
    u16* dst; const float* A; const float* Bm = nullptr; int t, nks;
    if (gid < 12800)      { dst = wy_swz;  t = gid;        nks = 10; A = Wy; }
    else if (gid < 25600) { dst = wh_swz;  t = gid-12800;  nks = 10; A = Wh; }
    else                  { dst = wpx_swz; t = gid-25600;  nks = 20; A = Wp; Bm = Wx; }
    int ks   = (t/64) % nks;
    int tile = t/(nks*64);
    int lane = t & 63;
    int d  = tile*16 + (lane & 15);
    int kb = ks*32 + (lane>>4)*8;
    u32 pk[4];
    #pragma unroll
    for (int jj=0; jj<4; jj++){
        int k0 = kb + 2*jj, k1 = k0 + 1;
        float v0, v1;
        if (Bm){ v0 = (k0 < 320) ? wval(A,d,k0) : wval(Bm,d,k0-320);
                 v1 = (k1 < 320) ? wval(A,d,k1) : wval(Bm,d,k1-320); }
        else   { v0 = wval(A,d,k0); v1 = wval(A,d,k1); }
        pk[jj] = (u32)f2bf(v0) | ((u32)f2bf(v1) << 16);
    }
    uint4 u; u.x = pk[0]; u.y = pk[1]; u.z = pk[2]; u.w = pk[3];
    ((uint4*)dst)[t] = u;
}

// ---------------- K1: Whh = h_n @ Wh^T  ->  bf16 [B][320] -------------------
__global__ __launch_bounds__(256,3) void k_whh(const float* __restrict__ hn,
        const u16* __restrict__ wh_swz, u16* __restrict__ whh)
{
    __shared__ __align__(16) u16 A[64*328];
    int tid = threadIdx.x;
    int rb = blockIdx.x >> 1, half = blockIdx.x & 1;
    int m0 = rb*64;
    for (int i = tid; i < 9600; i += 256){
        int r = i/150, c = (i%150)*2;
        float2 v = *(const float2*)(hn + (size_t)(m0+r)*300 + c);
        *(u32*)&A[r*328 + c] = pkbf(v.x, v.y);
    }
    for (int i = tid; i < 64*14; i += 256){ int r = i/14, c = 300 + (i%14)*2; *(u32*)&A[r*328+c] = 0; }
    __syncthreads();
    int w = tid>>6, lane = tid&63, lo = lane&15, hi = lane>>4;
    f32x4 acc[10];
    #pragma unroll
    for (int t=0; t<10; t++) acc[t] = (f32x4){0.f,0.f,0.f,0.f};
    const bf16x8* wsz = (const bf16x8*)wh_swz;
    for (int ks=0; ks<10; ks++){
        bf16x8 aF = *(const bf16x8*)&A[(w*16+lo)*328 + ks*32 + hi*8];
        #pragma unroll
        for (int t=0; t<10; t++){
            int nt = half*10 + t;
            bf16x8 bF = wsz[(nt*10+ks)*64 + lane];
            acc[t] = __builtin_amdgcn_mfma_f32_16x16x32_bf16(aF, bF, acc[t], 0,0,0);
        }
    }
    #pragma unroll
    for (int t=0; t<10; t++)
      #pragma unroll
      for (int rg=0; rg<4; rg++){
        int m = m0 + w*16 + hi*4 + rg;
        whh[(size_t)m*320 + (half*10+t)*16 + lo] = f2bf(acc[t][rg]);
      }
}

// ---------------- K2: fused attention main (1 batch / block) ----------------
// Ylds: transposed bf16 [row=l (64)][e (384 u16)], XOR-swizzled:
//   element (l, e) lives at byte  l*768 + ((2*e) ^ ((l&15)<<4))
__global__ __launch_bounds__(256,3) void k_attn(const float* __restrict__ Y,
        const u16* __restrict__ whh, const u16* __restrict__ wy_swz,
        const float* __restrict__ w_pad, u16* __restrict__ r_out)
{
    __shared__ __align__(16) u16 Ylds[64*384];     // 49152 B
    __shared__ float whh_s[320];
    __shared__ float w_s[320];
    __shared__ float s_red[4][64];
    __shared__ float alpha_s[64];
    char* Yb8 = (char*)Ylds;
    int tid = threadIdx.x;
    int b = blockIdx.x;
    int w = tid>>6, lane = tid&63, lo = lane&15, hi = lane>>4;
    const float* Yb = Y + (size_t)b*15000;

    // ---- staging: coalesced row-pair loads -> cvt_pk -> swizzled u32 writes ----
    // quad task t (0..1799): e2 = t/12 (e-pair), l4 = (t%12)*4 (rows l4..l4+3)
    #pragma unroll
    for (int it=0; it<7; it++){
        int t = tid + it*256;
        int e2 = t/12, l4 = (t%12)*4;
        const float* pA = Yb + e2*100 + l4;        // row e=2*e2 (16B aligned)
        float4 a  = *(const float4*)pA;
        float2 b0 = *(const float2*)(pA + 50);     // row e=2*e2+1 (8B aligned)
        float2 b1 = *(const float2*)(pA + 52);
        float av[4] = {a.x, a.y, a.z, a.w};
        float bv[4] = {b0.x, b0.y, b1.x, b1.y};
        #pragma unroll
        for (int j=0; j<4; j++){
            int row = l4 + j;
            *(u32*)(Yb8 + row*768 + ((e2*4) ^ ((row&15)<<4))) = pkbf(av[j], bv[j]);
        }
    }
    for (int t = tid + 1792; t < 1800; t += 256){  // remainder tasks
        int e2 = t/12, l4 = (t%12)*4;
        const float* pA = Yb + e2*100 + l4;
        float4 a  = *(const float4*)pA;
        float2 b0 = *(const float2*)(pA + 50);
        float2 b1 = *(const float2*)(pA + 52);
        float av[4] = {a.x, a.y, a.z, a.w};
        float bv[4] = {b0.x, b0.y, b1.x, b1.y};
        #pragma unroll
        for (int j=0; j<4; j++){
            int row = l4 + j;
            *(u32*)(Yb8 + row*768 + ((e2*4) ^ ((row&15)<<4))) = pkbf(av[j], bv[j]);
        }
    }
    if (tid < 150){                                // tail rows l=48,49
        int e2 = tid;
        float2 a = *(const float2*)(Yb + e2*100 + 48);
        float2 c = *(const float2*)(Yb + e2*100 + 98);
        *(u32*)(Yb8 + 48*768 + ((e2*4) ^ ((48&15)<<4))) = pkbf(a.x, c.x);
        *(u32*)(Yb8 + 49*768 + ((e2*4) ^ ((49&15)<<4))) = pkbf(a.y, c.y);
    }
    for (int i = tid; i < 500; i += 256){          // zero e in [300,320), rows 0..49
        int row = i/10, e2 = 150 + i%10;
        *(u32*)(Yb8 + row*768 + ((e2*4) ^ ((row&15)<<4))) = 0;
    }
    for (int i = tid; i < 160; i += 256){
        u32 z = *(const u32*)&whh[(size_t)b*320 + 2*i];
        whh_s[2*i]   = bf2f((u16)(z & 0xffff));
        whh_s[2*i+1] = bf2f((u16)(z >> 16));
    }
    for (int i = tid; i < 320; i += 256) w_s[i] = w_pad[i];
    __syncthreads();

    // ---- G = Wy * Yb, two q-passes to bound register pressure ----
    const bf16x8* wyf = (const bf16x8*)wy_swz;
    float sp[4] = {0.f,0.f,0.f,0.f};

#define GEMM_PASS(Q0, NQ)                                                      \
    {                                                                          \
        f32x4 acc[NQ][4];                                                      \
        _Pragma("unroll") for (int q=0;q<NQ;q++)                               \
            _Pragma("unroll") for (int c=0;c<4;c++)                            \
                acc[q][c] = (f32x4){0.f,0.f,0.f,0.f};                          \
        _Pragma("unroll 1")                                                    \
        for (int ks=0; ks<10; ks++){                                           \
            bf16x8 aF[NQ];                                                     \
            _Pragma("unroll") for (int q=0;q<NQ;q++)                           \
                aF[q] = wyf[((w + 4*((Q0)+q))*10 + ks)*64 + lane];             \
            bf16x8 bF[4];                                                      \
            _Pragma("unroll") for (int c=0;c<4;c++){                           \
                int row = c*16 + lo;                                           \
                bF[c] = *(const bf16x8*)(Yb8 + row*768 +                       \
                          ((ks*64 + hi*16) ^ ((row&15)<<4)));                  \
            }                                                                  \
            _Pragma("unroll") for (int q=0;q<NQ;q++)                           \
                _Pragma("unroll") for (int c=0;c<4;c++)                        \
                    acc[q][c] = __builtin_amdgcn_mfma_f32_16x16x32_bf16(       \
                        aF[q], bF[c], acc[q][c], 0,0,0);                       \
        }                                                                      \
        _Pragma("unroll") for (int q=0;q<NQ;q++)                               \
            _Pragma("unroll") for (int rg=0;rg<4;rg++){                        \
                int d = (w + 4*((Q0)+q))*16 + hi*4 + rg;                       \
                float wh = whh_s[d], wd_ = w_s[d];                             \
                _Pragma("unroll") for (int c=0;c<4;c++)                        \
                    sp[c] += wd_ * fast_tanh(acc[q][c][rg] + wh);              \
            }                                                                  \
    }

    GEMM_PASS(0, 3)
    GEMM_PASS(3, 2)
#undef GEMM_PASS

    #pragma unroll
    for (int c=0;c<4;c++){
        sp[c] += __shfl_xor(sp[c], 16);
        sp[c] += __shfl_xor(sp[c], 32);
    }
    if (lane < 16){
        #pragma unroll
        for (int c=0;c<4;c++) s_red[w][c*16 + lane] = sp[c];
    }
    __syncthreads();

    // ---- softmax over l (wave 0) ----
    if (w == 0){
        float sv = (lane < 50)
            ? (s_red[0][lane] + s_red[1][lane] + s_red[2][lane] + s_red[3][lane])
            : -1e30f;
        float mx = sv;
        #pragma unroll
        for (int off=32; off; off>>=1) mx = fmaxf(mx, __shfl_xor(mx, off));
        float pv = (lane < 50) ? __expf(sv - mx) : 0.f;
        float sm = pv;
        #pragma unroll
        for (int off=32; off; off>>=1) sm += __shfl_xor(sm, off);
        alpha_s[lane] = pv / sm;
    }
    __syncthreads();

    // ---- r[d] = sum_l Y[d][l] * alpha[l] ----
    if (tid < 160){
        float r0 = 0.f, r1 = 0.f;
        if (tid < 150){
            #pragma unroll 10
            for (int l=0; l<50; l++){
                u32 z = *(const u32*)(Yb8 + l*768 + ((tid*4) ^ ((l&15)<<4)));
                float a_ = alpha_s[l];
                r0 += a_ * bf2f((u16)(z & 0xffff));
                r1 += a_ * bf2f((u16)(z >> 16));
            }
        }
        *(u32*)&r_out[(size_t)b*320 + 2*tid] = pkbf(r0, r1);
    }
}

// ---------------- K3: h = tanh([r|hn] @ [Wp|Wx]^T), 32 rows/block -----------
__global__ __launch_bounds__(256,3) void k_out(const u16* __restrict__ r_in,
        const float* __restrict__ hn, const u16* __restrict__ wpx_swz,
        float* __restrict__ out)
{
    __shared__ __align__(16) u16 A[32*648];
    int tid = threadIdx.x;
    int m0 = blockIdx.x*32;
    for (int i = tid; i < 32*40; i += 256){
        int r = i/40, c8 = (i%40)*8;
        uint4 v = *(const uint4*)&r_in[(size_t)(m0+r)*320 + c8];
        *(uint4*)&A[r*648 + c8] = v;
    }
    for (int i = tid; i < 32*150; i += 256){
        int r = i/150, c = (i%150)*2;
        float2 v = *(const float2*)(hn + (size_t)(m0+r)*300 + c);
        *(u32*)&A[r*648 + 320 + c] = pkbf(v.x, v.y);
    }
    for (int i = tid; i < 32*14; i += 256){ int r = i/14, c = 620 + (i%14)*2; *(u32*)&A[r*648+c] = 0; }
    __syncthreads();
    int w = tid>>6, lane = tid&63, lo = lane&15, hi = lane>>4;
    int wm = w & 1, wn = w >> 1;
    f32x4 acc[10];
    #pragma unroll
    for (int t=0; t<10; t++) acc[t] = (f32x4){0.f,0.f,0.f,0.f};
    const bf16x8* wsz = (const bf16x8*)wpx_swz;
    for (int ks=0; ks<20; ks++){
        bf16x8 aF = *(const bf16x8*)&A[(wm*16+lo)*648 + ks*32 + hi*8];
        #pragma unroll
        for (int t=0; t<10; t++){
            int nt = wn*10 + t;
            bf16x8 bF = wsz[(nt*20+ks)*64 + lane];
            acc[t] = __builtin_amdgcn_mfma_f32_16x16x32_bf16(aF, bF, acc[t], 0,0,0);
        }
    }
    #pragma unroll
    for (int t=0; t<10; t++){
        int n = (wn*10+t)*16 + lo;
        if (n < 300){
            #pragma unroll
            for (int rg=0; rg<4; rg++){
                int m = m0 + wm*16 + hi*4 + rg;
                out[(size_t)m*300 + n] = fast_tanh(acc[t][rg]);
            }
        }
    }
}

extern "C" void kernel_launch(void* const* d_in, const int* in_sizes, int n_in,
                              void* d_out, int out_size, void* d_ws, size_t ws_size,
                              hipStream_t stream)
{
    const float* Y  = (const float*)d_in[0];
    const float* hn = (const float*)d_in[1];
    const float* Wy = (const float*)d_in[2];
    const float* Wh = (const float*)d_in[3];
    const float* Wp = (const float*)d_in[4];
    const float* Wx = (const float*)d_in[5];
    const float* w  = (const float*)d_in[6];
    int B = in_sizes[1] / 300;                       // 16384

    char* ws = (char*)d_ws;
    u16*   wy_swz  = (u16*)(ws + 0);                 // 204800 B
    u16*   wh_swz  = (u16*)(ws + 204800);            // 204800 B
    u16*   wpx_swz = (u16*)(ws + 409600);            // 409600 B
    float* w_pad   = (float*)(ws + 819200);          // 1280 B
    u16*   whh     = (u16*)(ws + 820480);            // B*320*2
    u16*   r_ws    = (u16*)(ws + 820480 + (size_t)B*640);

    k_prep<<<200, 256, 0, stream>>>(Wy, Wh, Wp, Wx, w, wy_swz, wh_swz, wpx_swz, w_pad);
    k_whh <<<(B/64)*2, 256, 0, stream>>>(hn, wh_swz, whh);
    k_attn<<<B, 256, 0, stream>>>(Y, whh, wy_swz, w_pad, r_ws);
    k_out <<<B/32, 256, 0, stream>>>(r_ws, hn, wpx_swz, (float*)d_out);
}

// Round 4
// 494.483 us; speedup vs baseline: 1.5094x; 1.2316x over previous
//
#include <hip/hip_runtime.h>
#include <hip/hip_bf16.h>

typedef __attribute__((ext_vector_type(8))) short bf16x8;
typedef __attribute__((ext_vector_type(4))) float f32x4;
typedef unsigned short u16;
typedef unsigned int u32;

__device__ __forceinline__ u16 f2bf(float f){
    u32 u; __builtin_memcpy(&u,&f,4);
    u = (u + 0x7FFFu + ((u>>16)&1u)) >> 16;
    return (u16)u;
}
__device__ __forceinline__ float bf2f(u16 h){
    u32 u = ((u32)h)<<16; float f; __builtin_memcpy(&f,&u,4); return f;
}
__device__ __forceinline__ u32 pkbf(float a, float b){
    __hip_bfloat162 h = __float22bfloat162_rn(float2{a,b});
    u32 r; __builtin_memcpy(&r,&h,4); return r;
}
// tanh via v_exp_f32 (2^x) + v_rcp_f32 — no slow div sequence
__device__ __forceinline__ float fast_tanh(float x){
    float e = __builtin_amdgcn_exp2f(x * 2.8853900817779268f);
    return 1.f - 2.f*__builtin_amdgcn_rcpf(e + 1.f);
}
__device__ __forceinline__ float wval(const float* W, int d, int e){
    return (d<300 && e<300) ? W[d*300+e] : 0.f;
}
// LDS swizzle: 16B-slot permutation, bijective per 16-row group; spreads both
// the 12-row staging writes and the 16-row bF reads across distinct slots.
__device__ __forceinline__ int yslot(int row){
    return (((row&15) ^ ((row>>2)&3) ^ ((row&48)>>2))) << 4;
}

// ---------------- K0: weight prep (swizzle to MFMA fragment order) ----------
// frag[tile][ks][lane][j] = W[d=tile*16+(lane&15)][e=ks*32+(lane>>4)*8+j]
__global__ void k_prep(const float* __restrict__ Wy, const float* __restrict__ Wh,
                       const float* __restrict__ Wp, const float* __restrict__ Wx,
                       const float* __restrict__ w,
                       u16* __restrict__ wy_swz, u16* __restrict__ wh_swz,
                       u16* __restrict__ wpx_swz, float* __restrict__ w_pad)
{
    int gid = blockIdx.x*256 + threadIdx.x;
    if (gid < 320) w_pad[gid] = (gid < 300) ? w[gid] : 0.f;
    u16* dst; const float* A; const float* Bm = nullptr; int t, nks;
    if (gid < 12800)      { dst = wy_swz;  t = gid;        nks = 10; A = Wy; }
    else if (gid < 25600) { dst = wh_swz;  t = gid-12800;  nks = 10; A = Wh; }
    else                  { dst = wpx_swz; t = gid-25600;  nks = 20; A = Wp; Bm = Wx; }
    int ks   = (t/64) % nks;
    int tile = t/(nks*64);
    int lane = t & 63;
    int d  = tile*16 + (lane & 15);
    int kb = ks*32 + (lane>>4)*8;
    u32 pk[4];
    #pragma unroll
    for (int jj=0; jj<4; jj++){
        int k0 = kb + 2*jj, k1 = k0 + 1;
        float v0, v1;
        if (Bm){ v0 = (k0 < 320) ? wval(A,d,k0) : wval(Bm,d,k0-320);
                 v1 = (k1 < 320) ? wval(A,d,k1) : wval(Bm,d,k1-320); }
        else   { v0 = wval(A,d,k0); v1 = wval(A,d,k1); }
        pk[jj] = (u32)f2bf(v0) | ((u32)f2bf(v1) << 16);
    }
    uint4 u; u.x = pk[0]; u.y = pk[1]; u.z = pk[2]; u.w = pk[3];
    ((uint4*)dst)[t] = u;
}

// ---------------- K1: Whh = h_n @ Wh^T  ->  bf16 [B][320] -------------------
__global__ __launch_bounds__(256,3) void k_whh(const float* __restrict__ hn,
        const u16* __restrict__ wh_swz, u16* __restrict__ whh)
{
    __shared__ __align__(16) u16 A[64*328];
    int tid = threadIdx.x;
    int rb = blockIdx.x >> 1, half = blockIdx.x & 1;
    int m0 = rb*64;
    for (int i = tid; i < 9600; i += 256){
        int r = i/150, c = (i%150)*2;
        float2 v = *(const float2*)(hn + (size_t)(m0+r)*300 + c);
        *(u32*)&A[r*328 + c] = pkbf(v.x, v.y);
    }
    for (int i = tid; i < 64*14; i += 256){ int r = i/14, c = 300 + (i%14)*2; *(u32*)&A[r*328+c] = 0; }
    __syncthreads();
    int w = tid>>6, lane = tid&63, lo = lane&15, hi = lane>>4;
    f32x4 acc[10];
    #pragma unroll
    for (int t=0; t<10; t++) acc[t] = (f32x4){0.f,0.f,0.f,0.f};
    const bf16x8* wsz = (const bf16x8*)wh_swz;
    for (int ks=0; ks<10; ks++){
        bf16x8 aF = *(const bf16x8*)&A[(w*16+lo)*328 + ks*32 + hi*8];
        #pragma unroll
        for (int t=0; t<10; t++){
            int nt = half*10 + t;
            bf16x8 bF = wsz[(nt*10+ks)*64 + lane];
            acc[t] = __builtin_amdgcn_mfma_f32_16x16x32_bf16(aF, bF, acc[t], 0,0,0);
        }
    }
    #pragma unroll
    for (int t=0; t<10; t++)
      #pragma unroll
      for (int rg=0; rg<4; rg++){
        int m = m0 + w*16 + hi*4 + rg;
        whh[(size_t)m*320 + (half*10+t)*16 + lo] = f2bf(acc[t][rg]);
      }
}

// ---------------- K2: fused attention main (1 batch / block) ----------------
// Ylds: transposed bf16 [row=l (64)][e (384 u16)]; element (l,e) at byte
//   l*768 + ((2e) ^ yslot(l))
__global__ __launch_bounds__(256,3) void k_attn(const float* __restrict__ Y,
        const u16* __restrict__ whh, const u16* __restrict__ wy_swz,
        const float* __restrict__ w_pad, u16* __restrict__ r_out)
{
    __shared__ __align__(16) u16 Ylds[64*384];     // 49152 B
    __shared__ float whh_s[320];
    __shared__ float w_s[320];
    __shared__ float s_red[4][64];
    __shared__ float alpha_s[64];
    char* Yb8 = (char*)Ylds;
    int tid = threadIdx.x;
    int b = blockIdx.x;
    int w = tid>>6, lane = tid&63, lo = lane&15, hi = lane>>4;
    const float* Yb = Y + (size_t)b*15000;
    const float C2L = 2.8853900817779268f;         // 2*log2(e)

    // ---- staging: coalesced row-pair loads -> cvt_pk -> swizzled u32 writes ----
    // quad task t (0..1799): e2 = t/12 (e-pair), l4 = (t%12)*4 (rows l4..l4+3)
    #pragma unroll
    for (int it=0; it<7; it++){
        int t = tid + it*256;
        int e2 = t/12, l4 = (t%12)*4;
        const float* pA = Yb + e2*100 + l4;        // row e=2*e2 (16B aligned)
        float4 a  = *(const float4*)pA;
        float2 b0 = *(const float2*)(pA + 50);     // row e=2*e2+1
        float2 b1 = *(const float2*)(pA + 52);
        float av[4] = {a.x, a.y, a.z, a.w};
        float bv[4] = {b0.x, b0.y, b1.x, b1.y};
        #pragma unroll
        for (int j=0; j<4; j++){
            int row = l4 + j;
            *(u32*)(Yb8 + row*768 + ((e2*4) ^ yslot(row))) = pkbf(av[j], bv[j]);
        }
    }
    for (int t = tid + 1792; t < 1800; t += 256){  // remainder tasks
        int e2 = t/12, l4 = (t%12)*4;
        const float* pA = Yb + e2*100 + l4;
        float4 a  = *(const float4*)pA;
        float2 b0 = *(const float2*)(pA + 50);
        float2 b1 = *(const float2*)(pA + 52);
        float av[4] = {a.x, a.y, a.z, a.w};
        float bv[4] = {b0.x, b0.y, b1.x, b1.y};
        #pragma unroll
        for (int j=0; j<4; j++){
            int row = l4 + j;
            *(u32*)(Yb8 + row*768 + ((e2*4) ^ yslot(row))) = pkbf(av[j], bv[j]);
        }
    }
    if (tid < 150){                                // tail rows l=48,49
        int e2 = tid;
        float2 a = *(const float2*)(Yb + e2*100 + 48);
        float2 c = *(const float2*)(Yb + e2*100 + 98);
        *(u32*)(Yb8 + 48*768 + ((e2*4) ^ yslot(48))) = pkbf(a.x, c.x);
        *(u32*)(Yb8 + 49*768 + ((e2*4) ^ yslot(49))) = pkbf(a.y, c.y);
    }
    for (int i = tid; i < 500; i += 256){          // zero e in [300,320), rows 0..49
        int row = i/10, e2 = 150 + i%10;
        *(u32*)(Yb8 + row*768 + ((e2*4) ^ yslot(row))) = 0;
    }
    for (int i = tid; i < 160; i += 256){
        u32 z = *(const u32*)&whh[(size_t)b*320 + 2*i];
        whh_s[2*i]   = bf2f((u16)(z & 0xffff));
        whh_s[2*i+1] = bf2f((u16)(z >> 16));
    }
    for (int i = tid; i < 320; i += 256) w_s[i] = w_pad[i];
    __syncthreads();

    // ---- G = Wy * Yb, two q-passes, 2-deep pipelined fragment loads ----
    const bf16x8* wyf = (const bf16x8*)wy_swz;
    float sp[4] = {0.f,0.f,0.f,0.f};
    float swd = 0.f;
    int rb_[4], sl_[4];
    #pragma unroll
    for (int c=0;c<4;c++){ int row=c*16+lo; rb_[c]=row*768; sl_[c]=yslot(row); }
    int hi16 = hi*16;

#define GEMM_PASS(Q0, NQ)                                                      \
    {                                                                          \
        f32x4 acc[NQ][4];                                                      \
        _Pragma("unroll") for (int q=0;q<NQ;q++)                               \
            _Pragma("unroll") for (int c=0;c<4;c++)                            \
                acc[q][c] = (f32x4){0.f,0.f,0.f,0.f};                          \
        bf16x8 A0[NQ], A1[NQ], B0[4], B1[4];                                   \
        _Pragma("unroll") for (int q=0;q<NQ;q++)                               \
            A0[q] = wyf[((w+4*((Q0)+q))*10)*64 + lane];                        \
        _Pragma("unroll") for (int c=0;c<4;c++)                                \
            B0[c] = *(const bf16x8*)(Yb8 + rb_[c] + (hi16 ^ sl_[c]));          \
        _Pragma("unroll 1")                                                    \
        for (int kk=0; kk<5; kk++){                                            \
            int k1 = 2*kk+1, k2 = 2*kk+2;                                      \
            int k2c = (k2 < 10) ? k2 : 0;                                      \
            _Pragma("unroll") for (int q=0;q<NQ;q++)                           \
                A1[q] = wyf[((w+4*((Q0)+q))*10 + k1)*64 + lane];               \
            _Pragma("unroll") for (int c=0;c<4;c++)                            \
                B1[c] = *(const bf16x8*)(Yb8 + rb_[c] + ((k1*64+hi16) ^ sl_[c])); \
            _Pragma("unroll") for (int q=0;q<NQ;q++)                           \
                _Pragma("unroll") for (int c=0;c<4;c++)                        \
                    acc[q][c] = __builtin_amdgcn_mfma_f32_16x16x32_bf16(       \
                        A0[q], B0[c], acc[q][c], 0,0,0);                       \
            _Pragma("unroll") for (int q=0;q<NQ;q++)                           \
                A0[q] = wyf[((w+4*((Q0)+q))*10 + k2)*64 + lane];               \
            _Pragma("unroll") for (int c=0;c<4;c++)                            \
                B0[c] = *(const bf16x8*)(Yb8 + rb_[c] + ((k2c*64+hi16) ^ sl_[c])); \
            _Pragma("unroll") for (int q=0;q<NQ;q++)                           \
                _Pragma("unroll") for (int c=0;c<4;c++)                        \
                    acc[q][c] = __builtin_amdgcn_mfma_f32_16x16x32_bf16(       \
                        A1[q], B1[c], acc[q][c], 0,0,0);                       \
        }                                                                      \
        _Pragma("unroll") for (int q=0;q<NQ;q++)                               \
            _Pragma("unroll") for (int rg=0;rg<4;rg++){                        \
                int d = (w + 4*((Q0)+q))*16 + hi*4 + rg;                       \
                float wh = whh_s[d], wd_ = w_s[d];                             \
                float whc = wh*C2L, wd2n = -2.f*wd_;                           \
                swd += wd_;                                                    \
                _Pragma("unroll") for (int c=0;c<4;c++){                       \
                    float targ = __builtin_fmaf(acc[q][c][rg], C2L, whc);      \
                    float e2x  = __builtin_amdgcn_exp2f(targ);                 \
                    float rc   = __builtin_amdgcn_rcpf(e2x + 1.f);             \
                    sp[c] = __builtin_fmaf(wd2n, rc, sp[c]);                   \
                }                                                              \
            }                                                                  \
    }

    GEMM_PASS(0, 3)
    GEMM_PASS(3, 2)
#undef GEMM_PASS

    #pragma unroll
    for (int c=0;c<4;c++){
        sp[c] += swd;                 // sum w*tanh = sum(w) - 2*sum(w*rcp)
        sp[c] += __shfl_xor(sp[c], 16);
        sp[c] += __shfl_xor(sp[c], 32);
    }
    if (lane < 16){
        #pragma unroll
        for (int c=0;c<4;c++) s_red[w][c*16 + lane] = sp[c];
    }
    __syncthreads();

    // ---- softmax over l (wave 0) ----
    if (w == 0){
        float sv = (lane < 50)
            ? (s_red[0][lane] + s_red[1][lane] + s_red[2][lane] + s_red[3][lane])
            : -1e30f;
        float mx = sv;
        #pragma unroll
        for (int off=32; off; off>>=1) mx = fmaxf(mx, __shfl_xor(mx, off));
        float pv = (lane < 50) ? __builtin_amdgcn_exp2f((sv - mx)*1.4426950408889634f) : 0.f;
        float sm = pv;
        #pragma unroll
        for (int off=32; off; off>>=1) sm += __shfl_xor(sm, off);
        alpha_s[lane] = pv * __builtin_amdgcn_rcpf(sm);
    }
    __syncthreads();

    // ---- r[d] = sum_l Y[d][l] * alpha[l] ----
    if (tid < 160){
        float r0 = 0.f, r1 = 0.f;
        if (tid < 150){
            #pragma unroll 10
            for (int l=0; l<50; l++){
                u32 z = *(const u32*)(Yb8 + l*768 + ((tid*4) ^ yslot(l)));
                float a_ = alpha_s[l];
                r0 += a_ * bf2f((u16)(z & 0xffff));
                r1 += a_ * bf2f((u16)(z >> 16));
            }
        }
        *(u32*)&r_out[(size_t)b*320 + 2*tid] = pkbf(r0, r1);
    }
}

// ---------------- K3: h = tanh([r|hn] @ [Wp|Wx]^T), 32 rows/block -----------
__global__ __launch_bounds__(256,3) void k_out(const u16* __restrict__ r_in,
        const float* __restrict__ hn, const u16* __restrict__ wpx_swz,
        float* __restrict__ out)
{
    __shared__ __align__(16) u16 A[32*648];
    int tid = threadIdx.x;
    int m0 = blockIdx.x*32;
    for (int i = tid; i < 32*40; i += 256){
        int r = i/40, c8 = (i%40)*8;
        uint4 v = *(const uint4*)&r_in[(size_t)(m0+r)*320 + c8];
        *(uint4*)&A[r*648 + c8] = v;
    }
    for (int i = tid; i < 32*150; i += 256){
        int r = i/150, c = (i%150)*2;
        float2 v = *(const float2*)(hn + (size_t)(m0+r)*300 + c);
        *(u32*)&A[r*648 + 320 + c] = pkbf(v.x, v.y);
    }
    for (int i = tid; i < 32*14; i += 256){ int r = i/14, c = 620 + (i%14)*2; *(u32*)&A[r*648+c] = 0; }
    __syncthreads();
    int w = tid>>6, lane = tid&63, lo = lane&15, hi = lane>>4;
    int wm = w & 1, wn = w >> 1;
    f32x4 acc[10];
    #pragma unroll
    for (int t=0; t<10; t++) acc[t] = (f32x4){0.f,0.f,0.f,0.f};
    const bf16x8* wsz = (const bf16x8*)wpx_swz;
    for (int ks=0; ks<20; ks++){
        bf16x8 aF = *(const bf16x8*)&A[(wm*16+lo)*648 + ks*32 + hi*8];
        #pragma unroll
        for (int t=0; t<10; t++){
            int nt = wn*10 + t;
            bf16x8 bF = wsz[(nt*20+ks)*64 + lane];
            acc[t] = __builtin_amdgcn_mfma_f32_16x16x32_bf16(aF, bF, acc[t], 0,0,0);
        }
    }
    #pragma unroll
    for (int t=0; t<10; t++){
        int n = (wn*10+t)*16 + lo;
        if (n < 300){
            #pragma unroll
            for (int rg=0; rg<4; rg++){
                int m = m0 + wm*16 + hi*4 + rg;
                out[(size_t)m*300 + n] = fast_tanh(acc[t][rg]);
            }
        }
    }
}

extern "C" void kernel_launch(void* const* d_in, const int* in_sizes, int n_in,
                              void* d_out, int out_size, void* d_ws, size_t ws_size,
                              hipStream_t stream)
{
    const float* Y  = (const float*)d_in[0];
    const float* hn = (const float*)d_in[1];
    const float* Wy = (const float*)d_in[2];
    const float* Wh = (const float*)d_in[3];
    const float* Wp = (const float*)d_in[4];
    const float* Wx = (const float*)d_in[5];
    const float* w  = (const float*)d_in[6];
    int B = in_sizes[1] / 300;                       // 16384

    char* ws = (char*)d_ws;
    u16*   wy_swz  = (u16*)(ws + 0);                 // 204800 B
    u16*   wh_swz  = (u16*)(ws + 204800);            // 204800 B
    u16*   wpx_swz = (u16*)(ws + 409600);            // 409600 B
    float* w_pad   = (float*)(ws + 819200);          // 1280 B
    u16*   whh     = (u16*)(ws + 820480);            // B*320*2
    u16*   r_ws    = (u16*)(ws + 820480 + (size_t)B*640);

    k_prep<<<200, 256, 0, stream>>>(Wy, Wh, Wp, Wx, w, wy_swz, wh_swz, wpx_swz, w_pad);
    k_whh <<<(B/64)*2, 256, 0, stream>>>(hn, wh_swz, whh);
    k_attn<<<B, 256, 0, stream>>>(Y, whh, wy_swz, w_pad, r_ws);
    k_out <<<B/32, 256, 0, stream>>>(r_ws, hn, wpx_swz, (float*)d_out);
}